// Round 6
// baseline (644.629 us; speedup 1.0000x reference)
//
#include <hip/hip_runtime.h>
#include <stdint.h>

typedef unsigned short u16;
typedef u16 u16x4 __attribute__((ext_vector_type(4)));
typedef u16 u16x8 __attribute__((ext_vector_type(8)));
typedef __bf16 bf16x8 __attribute__((ext_vector_type(8)));
typedef float f32x4 __attribute__((ext_vector_type(4)));
typedef float f32x16 __attribute__((ext_vector_type(16)));

#define NE   256
#define NPOS 40960     // 32*64*4*5
#define QLD  1536      // QKV row stride

__device__ __forceinline__ float bf2f(u16 h) {
  union { unsigned u; float f; } c; c.u = ((unsigned)h) << 16; return c.f;
}
__device__ __forceinline__ u16 f2bf(float f) {
  union { float f; unsigned u; } c; c.f = f;
  unsigned u = c.u;
  return (u16)((u + 0x7FFFu + ((u >> 16) & 1u)) >> 16);
}
__device__ __forceinline__ unsigned pkbf(float a, float b) {
  unsigned r;
  asm("v_cvt_pk_bf16_f32 %0, %1, %2" : "=v"(r) : "v"(a), "v"(b));
  return r;
}
__device__ __forceinline__ void gll16(const void* g, void* l) {
  __builtin_amdgcn_global_load_lds(
      (const __attribute__((address_space(1))) void*)g,
      (__attribute__((address_space(3))) void*)l, 16, 0, 0);
}
template<int N> __device__ __forceinline__ void waitvm() {
  if constexpr (N == 0)      asm volatile("s_waitcnt vmcnt(0)" ::: "memory");
  else if constexpr (N == 4) asm volatile("s_waitcnt vmcnt(4)" ::: "memory");
  else if constexpr (N == 6) asm volatile("s_waitcnt vmcnt(6)" ::: "memory");
}

// ---------------------------------------------------------------------------
// prep: xb[n][e] = bf16(x[b,s,e,h,w] + pos), n = ((b*64+s)*4+h)*5+w
// ---------------------------------------------------------------------------
__global__ __launch_bounds__(256) void prep_kernel(
    const float* __restrict__ x, const float* __restrict__ pos_s,
    const float* __restrict__ pos_h, const float* __restrict__ pos_w,
    u16* __restrict__ xb)
{
  __shared__ float Ls[256 * 21];
  const int bs = blockIdx.x;           // b*64+s
  const int s  = bs & 63;
  const int tid = threadIdx.x;
  const float* xp = x + (size_t)bs * 5120;
  for (int i = tid; i < 5120; i += 256) {
    int e = i / 20, hw = i % 20;
    int h = hw / 5, w = hw % 5;
    float v = xp[i] + pos_s[s * 256 + e] + pos_h[e * 4 + h] + pos_w[e * 5 + w];
    Ls[e * 21 + hw] = v;
  }
  __syncthreads();
  u16* op = xb + (size_t)bs * 20 * 256;
  for (int i = tid; i < 5120; i += 256) {
    int nl = i >> 8, e = i & 255;
    op[nl * 256 + e] = f2bf(Ls[e * 21 + nl]);
  }
}

// ---------------------------------------------------------------------------
// weight packing; wq rows scaled by 0.25 (attention SCALE folded in)
// ---------------------------------------------------------------------------
__global__ __launch_bounds__(256) void pack_qkv(
    const float* __restrict__ wq, const float* __restrict__ wkv, u16* __restrict__ dst)
{
  int i = blockIdx.x * 256 + threadIdx.x;      // 6*768*256
  int la = i / (768 * 256);
  int rem = i - la * (768 * 256);
  int r = rem >> 8, c = rem & 255;
  float v = (r < 256) ? wq[(size_t)la * 65536 + r * 256 + c] * 0.25f
                      : wkv[(size_t)la * 131072 + (r - 256) * 256 + c];
  dst[i] = f2bf(v);
}

// merged out-proj weights: dst[l][out][a*256+in] = wo_w[l][a][out][in]
__global__ __launch_bounds__(256) void pack_wo(
    const float* __restrict__ wo, u16* __restrict__ dst)
{
  int i = blockIdx.x * 256 + threadIdx.x;      // 2*256*768
  int l = i / 196608;
  int rem = i - l * 196608;
  int out = rem / 768, k = rem % 768;
  int a = k >> 8, in = k & 255;
  dst[i] = f2bf(wo[(size_t)(((l * 3 + a) * 256) + out) * 256 + in]);
}

__global__ __launch_bounds__(256) void pack_bias(
    const float* __restrict__ wo_b, float* __restrict__ bsum)
{
  int i = blockIdx.x * 256 + threadIdx.x;      // 512
  if (i < 512) {
    int l = i >> 8, c = i & 255;
    bsum[i] = wo_b[(l * 3 + 0) * 256 + c] + wo_b[(l * 3 + 1) * 256 + c]
            + wo_b[(l * 3 + 2) * 256 + c];
  }
}

// ---------------------------------------------------------------------------
// GEMM: C[M][N] = A[M][K] * B[N][K]^T   (A,B bf16; acc f32)
// 128 x BN tile, K = NKT*32, double-buffered LDS, counted-vmcnt prefetch.
// C written via LDS staging -> coalesced 16B stores.
// MODE 0: store bf16 at ldc; 3: Cb = bf16(acc+bias); 4: fused decode partial
// ---------------------------------------------------------------------------
template<int MODE, int BN, int NKT>
__global__ __launch_bounds__(256, 3) void gemm_bt(
    const u16* __restrict__ A, const u16* __restrict__ B,
    u16* __restrict__ Cb, const float* __restrict__ bias,
    const float* __restrict__ dw, float* __restrict__ logit,
    int ldc)
{
  constexpr int K    = NKT * 32;
  constexpr int NF   = BN / 32;         // n-frags per wave (wave covers BN/2)
  constexpr int LPT  = 2 + BN / 64;     // gll16 per thread per k-tile
  constexpr int ASZ  = 128 * 32;        // u16 per A buffer
  constexpr int BSZ  = BN * 32;
  constexpr int STG  = 2 * (ASZ + BSZ);
  constexpr int CPAD = 132;             // stride_dw=66 => khi groups 8 banks apart
  constexpr int CSZ  = 128 * CPAD;
  constexpr int SM   = (STG > CSZ ? STG : CSZ);
  static_assert(MODE != 4 || BN == 128, "");

  __shared__ alignas(16) u16 smem[SM];

  const int tid  = threadIdx.x;
  const int bm   = blockIdx.x, bn = blockIdx.y;
  const int lane = tid & 63, w = tid >> 6;
  const int wr   = (w >> 1) * 64, wc = (w & 1) * (BN / 2);
  const int r16  = lane & 15, khi = lane >> 4;

  f32x4 acc[4][NF] = {};

  const u16* gA = A + (size_t)bm * 128 * K;
  const u16* gB = B + (size_t)bn * BN * K;

  auto STAGE = [&](int kt, int which) {
    u16* As = smem + which * (ASZ + BSZ);
    u16* Bs = As + ASZ;
    const u16* tA = gA + kt * 32;
    const u16* tB = gB + kt * 32;
    #pragma unroll
    for (int r = 0; r < 2; ++r) {
      int i = tid + r * 256;             // 0..511
      int row = i >> 2, seg = (i & 3) << 3;
      gll16(tA + (size_t)row * K + seg, (char*)As + i * 16);
    }
    #pragma unroll
    for (int r = 0; r < BN / 64; ++r) {
      int i = tid + r * 256;             // 0..BN*4-1
      int row = i >> 2, seg = (i & 3) << 3;
      gll16(tB + (size_t)row * K + seg, (char*)Bs + i * 16);
    }
  };

  STAGE(0, 0);
  #pragma unroll
  for (int kt = 0; kt < NKT; ++kt) {
    const int cur = kt & 1;
    if (kt + 1 < NKT) { STAGE(kt + 1, cur ^ 1); waitvm<LPT>(); }
    else              { waitvm<0>(); }
    __builtin_amdgcn_s_barrier();
    asm volatile("" ::: "memory");

    const u16* As = smem + cur * (ASZ + BSZ);
    const u16* Bs = As + ASZ;
    bf16x8 af[4], bfr[NF];
    #pragma unroll
    for (int m = 0; m < 4; ++m)
      af[m] = *(const bf16x8*)(As + (wr + m * 16 + r16) * 32 + khi * 8);
    #pragma unroll
    for (int n = 0; n < NF; ++n)
      bfr[n] = *(const bf16x8*)(Bs + (wc + n * 16 + r16) * 32 + khi * 8);
    #pragma unroll
    for (int m = 0; m < 4; ++m)
      #pragma unroll
      for (int n = 0; n < NF; ++n)
        acc[m][n] = __builtin_amdgcn_mfma_f32_16x16x32_bf16(af[m], bfr[n], acc[m][n], 0, 0, 0);

    asm volatile("" ::: "memory");
    __builtin_amdgcn_s_barrier();
  }

  if constexpr (MODE == 4) {
    const int row0 = bm * 128 + wr + khi * 4;
    const int col0 = bn * BN + wc + r16;
    // fused decode: logit[r] += sum_c (acc + bias[c]) * dec_w[c]
    float dwv[NF], bvv[NF];
    #pragma unroll
    for (int n = 0; n < NF; ++n) {
      int c = col0 + n * 16;
      dwv[n] = dw[c];
      bvv[n] = bias[c];
    }
    #pragma unroll
    for (int m = 0; m < 4; ++m) {
      #pragma unroll
      for (int j = 0; j < 4; ++j) {
        float p = 0.f;
        #pragma unroll
        for (int n = 0; n < NF; ++n) p += (acc[m][n][j] + bvv[n]) * dwv[n];
        p += __shfl_xor(p, 1);
        p += __shfl_xor(p, 2);
        p += __shfl_xor(p, 4);
        p += __shfl_xor(p, 8);
        if (r16 == 0) atomicAdd(&logit[row0 + m * 16 + j], p);
      }
    }
  } else {
    // C epilogue: stage bf16 tile in LDS, then coalesced 16B row-major stores
    constexpr int HALVES = BN / 128;    // 1 (BN=128) or 2 (BN=256)
    u16* Cs = smem;
    asm volatile("s_waitcnt lgkmcnt(0)" ::: "memory");
    #pragma unroll
    for (int half = 0; half < HALVES; ++half) {
      if (half) __syncthreads();
      if (HALVES == 1 || (w & 1) == half) {
        const int cb = (HALVES == 1) ? wc : 0;
        #pragma unroll
        for (int m = 0; m < 4; ++m)
          #pragma unroll
          for (int n = 0; n < NF; ++n) {
            const int cc = cb + n * 16 + r16;
            const float bv = (MODE == 3) ? bias[bn * BN + half * 128 + cc] : 0.f;
            #pragma unroll
            for (int j = 0; j < 4; ++j)
              Cs[(wr + m * 16 + khi * 4 + j) * CPAD + cc] = f2bf(acc[m][n][j] + bv);
          }
      }
      __syncthreads();
      const int colbase = bn * BN + half * 128;
      #pragma unroll
      for (int t = 0; t < 8; ++t) {
        int i = tid + t * 256;           // 0..2047
        int r = i >> 4, c8 = (i & 15) << 3;
        const u16* s = Cs + r * CPAD + c8;
        union { u16x4 h[2]; u16x8 v; } uu;
        uu.h[0] = *(const u16x4*)s;
        uu.h[1] = *(const u16x4*)(s + 4);
        *(u16x8*)(Cb + (size_t)(bm * 128 + r) * ldc + colbase + c8) = uu.v;
      }
    }
  }
}

// ---------------------------------------------------------------------------
// seq-axis attention via MFMA. One wave = one (group g, head hd).
// QKV [NPOS][QLD] bf16 (q|k|v in cols 0..767). Writes Ob cols 0..255 (ld 768).
// ---------------------------------------------------------------------------
__global__ __launch_bounds__(256) void attn_seq_mfma(
    const u16* __restrict__ QKV, u16* __restrict__ Ob)
{
  const int w = threadIdx.x >> 6, lane = threadIdx.x & 63;
  const int wid = blockIdx.x * 4 + w;
  const int hd = wid & 15, g = wid >> 4;          // g in [0,640)
  const int gb = g / 20, gr = g % 20;
  const int nbase = gb * 1280 + gr;               // + pos*20
  const int lo = lane & 31, hi = lane >> 5;

  bf16x8 kf[2], qf[2];
  #pragma unroll
  for (int t = 0; t < 2; ++t) {
    size_t r = (size_t)(nbase + (lo + 32 * t) * 20) * QLD;
    kf[t] = *(const bf16x8*)(QKV + r + 256 + hd * 16 + hi * 8);
    qf[t] = *(const bf16x8*)(QKV + r +       hd * 16 + hi * 8);
  }
  union { u16 a[8]; bf16x8 v; } vt[4];
  #pragma unroll
  for (int c = 0; c < 4; ++c)
    #pragma unroll
    for (int j = 0; j < 8; ++j)
      vt[c].a[j] = QKV[(size_t)(nbase + (c * 16 + hi * 8 + j) * 20) * QLD
                       + 512 + hd * 16 + lo];

  f32x16 s00 = {}, s10 = {}, s01 = {}, s11 = {};   // s[kt][qt]
  s00 = __builtin_amdgcn_mfma_f32_32x32x16_bf16(kf[0], qf[0], s00, 0, 0, 0);
  s10 = __builtin_amdgcn_mfma_f32_32x32x16_bf16(kf[1], qf[0], s10, 0, 0, 0);
  s01 = __builtin_amdgcn_mfma_f32_32x32x16_bf16(kf[0], qf[1], s01, 0, 0, 0);
  s11 = __builtin_amdgcn_mfma_f32_32x32x16_bf16(kf[1], qf[1], s11, 0, 0, 0);

  auto run_qt = [&](f32x16 t0, f32x16 t1, int qt) {
    float m = -1e30f;
    #pragma unroll
    for (int r = 0; r < 16; ++r) { m = fmaxf(m, t0[r]); m = fmaxf(m, t1[r]); }
    m = fmaxf(m, __shfl_xor(m, 32));
    const float C = 1.4426950408889634f;           // log2(e); 0.25 folded in wq
    float mc = m * C;
    float sum = 0.f;
    #pragma unroll
    for (int r = 0; r < 16; ++r) {
      float p0 = __builtin_amdgcn_exp2f(t0[r] * C - mc);
      float p1 = __builtin_amdgcn_exp2f(t1[r] * C - mc);
      t0[r] = p0; t1[r] = p1; sum += p0; sum += p1;
    }
    sum += __shfl_xor(sum, 32);
    float inv = __builtin_amdgcn_rcpf(sum);
    #pragma unroll
    for (int r = 0; r < 16; ++r) { t0[r] *= inv; t1[r] *= inv; }

    f32x16 oa = {};
    #pragma unroll
    for (int c = 0; c < 4; ++c) {
      const int rb = 8 * (c & 1);
      const f32x16& tt = (c < 2) ? t0 : t1;
      unsigned X0 = pkbf(tt[rb + 0], tt[rb + 1]);
      unsigned X1 = pkbf(tt[rb + 2], tt[rb + 3]);
      unsigned Y0 = pkbf(tt[rb + 4], tt[rb + 5]);
      unsigned Y1 = pkbf(tt[rb + 6], tt[rb + 7]);
      unsigned X0p = __shfl_xor((int)X0, 32), X1p = __shfl_xor((int)X1, 32);
      unsigned Y0p = __shfl_xor((int)Y0, 32), Y1p = __shfl_xor((int)Y1, 32);
      union { unsigned u[4]; bf16x8 v; } pf;
      pf.u[0] = hi ? Y0p : X0;
      pf.u[1] = hi ? Y1p : X1;
      pf.u[2] = hi ? Y0  : X0p;
      pf.u[3] = hi ? Y1  : X1p;
      oa = __builtin_amdgcn_mfma_f32_32x32x16_bf16(vt[c].v, pf.v, oa, 0, 0, 0);
    }
    unsigned P0 = pkbf(oa[0], oa[1]);
    unsigned P1 = pkbf(oa[2], oa[3]);
    unsigned P2 = pkbf(oa[4], oa[5]);
    unsigned P3 = pkbf(oa[6], oa[7]);
    unsigned sP0 = __shfl_xor((int)P0, 32), sP1 = __shfl_xor((int)P1, 32);
    unsigned sP2 = __shfl_xor((int)P2, 32), sP3 = __shfl_xor((int)P3, 32);
    union { unsigned u[4]; u16x8 v; } ov;
    ov.u[0] = hi ? sP2 : P0;
    ov.u[1] = hi ? sP3 : P1;
    ov.u[2] = hi ? P2  : sP0;
    ov.u[3] = hi ? P3  : sP1;
    u16* po = Ob + (size_t)(nbase + (qt * 32 + lo) * 20) * 768 + hd * 16 + hi * 8;
    *(u16x8*)po = ov.v;
  };
  run_qt(s00, s10, 0);
  run_qt(s01, s11, 1);
}

// ---------------------------------------------------------------------------
// H (T=4, stride 5) and W (T=5, stride 1) attention, one thread per (n, head)
// ---------------------------------------------------------------------------
template<int T>
__device__ __forceinline__ void attn1(
    const u16* __restrict__ QKV, int n, int base, int stp, int hd,
    u16* __restrict__ po)
{
  const u16* qp = QKV + (size_t)n * QLD + hd * 16;
  u16x8 q0 = *(const u16x8*)(qp), q1 = *(const u16x8*)(qp + 8);
  float q[16];
  #pragma unroll
  for (int d = 0; d < 8; ++d) { q[d] = bf2f(q0[d]); q[d + 8] = bf2f(q1[d]); }

  float s[T];
  float m = -1e30f;
  #pragma unroll
  for (int j = 0; j < T; ++j) {
    const u16* kp = QKV + (size_t)(base + j * stp) * QLD + 256 + hd * 16;
    u16x8 k0 = *(const u16x8*)(kp), k1 = *(const u16x8*)(kp + 8);
    float a = 0.f;
    #pragma unroll
    for (int d = 0; d < 8; ++d) a += q[d] * bf2f(k0[d]) + q[d + 8] * bf2f(k1[d]);
    s[j] = a;
    m = fmaxf(m, a);
  }
  float sum = 0.f;
  float o[16];
  #pragma unroll
  for (int d = 0; d < 16; ++d) o[d] = 0.f;
  #pragma unroll
  for (int j = 0; j < T; ++j) {
    float pj = __expf(s[j] - m);
    sum += pj;
    const u16* vp = QKV + (size_t)(base + j * stp) * QLD + 512 + hd * 16;
    u16x8 w0 = *(const u16x8*)(vp), w1 = *(const u16x8*)(vp + 8);
    #pragma unroll
    for (int d = 0; d < 8; ++d) { o[d] += pj * bf2f(w0[d]); o[d + 8] += pj * bf2f(w1[d]); }
  }
  float inv = 1.0f / sum;
  u16x8 r0, r1;
  #pragma unroll
  for (int d = 0; d < 8; ++d) { r0[d] = f2bf(o[d] * inv); r1[d] = f2bf(o[d + 8] * inv); }
  *(u16x8*)(po)     = r0;
  *(u16x8*)(po + 8) = r1;
}

__global__ __launch_bounds__(256) void attn_hw(
    const u16* __restrict__ QKV, u16* __restrict__ Ob)
{
  const int tg = blockIdx.x * 256 + threadIdx.x;   // n*16 + hd
  const int hd = tg & 15, n = tg >> 4;
  int h  = (n % 20) / 5;
  int w5 = n % 5;
  attn1<4>(QKV,       n, n - h * 5, 5, hd, Ob + (size_t)n * 768 + 256 + hd * 16);
  attn1<5>(QKV + 768, n, n - w5,    1, hd, Ob + (size_t)n * 768 + 512 + hd * 16);
}

// ---------------------------------------------------------------------------
// final sigmoid over accumulated logits
// ---------------------------------------------------------------------------
__global__ __launch_bounds__(256) void sigmoid_kernel(
    const float* __restrict__ logit, const float* __restrict__ dec_b,
    float* __restrict__ out)
{
  int i = blockIdx.x * 256 + threadIdx.x;
  out[i] = 1.0f / (1.0f + __expf(-(logit[i] + dec_b[0])));
}

// ---------------------------------------------------------------------------
extern "C" void kernel_launch(void* const* d_in, const int* in_sizes, int n_in,
                              void* d_out, int out_size, void* d_ws, size_t ws_size,
                              hipStream_t stream) {
  const float* x     = (const float*)d_in[0];
  const float* pos_s = (const float*)d_in[1];
  const float* pos_h = (const float*)d_in[2];
  const float* pos_w = (const float*)d_in[3];
  const float* wq    = (const float*)d_in[4];   // (2,3,256,256)
  const float* wkv   = (const float*)d_in[5];   // (2,3,512,256)
  const float* wo_w  = (const float*)d_in[6];   // (2,3,256,256)
  const float* wo_b  = (const float*)d_in[7];   // (2,3,256)
  const float* dec_w = (const float*)d_in[8];   // (1,256)
  const float* dec_b = (const float*)d_in[9];   // (1,)
  float* out = (float*)d_out;

  char* ws = (char*)d_ws;
  u16*   xb    = (u16*)ws;                       // 20,971,520
  u16*   Ob    = (u16*)(ws + 20971520);          // 62,914,560
  u16*   QKV   = (u16*)(ws + 83886080);          // 40960*1536*2 = 125,829,120
  u16*   wqp   = (u16*)(ws + 209715200);         // 2,359,296
  u16*   wop   = (u16*)(ws + 212074496);         // 786,432
  float* bsum  = (float*)(ws + 212860928);       // 2,048
  float* logit = (float*)(ws + 212862976);       // 163,840  (end ~213 MB)

  prep_kernel<<<2048, 256, 0, stream>>>(x, pos_s, pos_h, pos_w, xb);
  pack_qkv<<<4608, 256, 0, stream>>>(wq, wkv, wqp);
  pack_wo<<<1536, 256, 0, stream>>>(wo_w, wop);
  pack_bias<<<2, 256, 0, stream>>>(wo_b, bsum);
  hipMemsetAsync(logit, 0, NPOS * sizeof(float), stream);

  for (int l = 0; l < 2; ++l) {
    // seq axis: QKV cols 0..767 (ldc 1536), then MFMA attention
    gemm_bt<0, 256, 8><<<dim3(320, 3), 256, 0, stream>>>(
        xb, wqp + (size_t)(l * 3) * 196608, QKV, nullptr, nullptr, nullptr, QLD);
    attn_seq_mfma<<<2560, 256, 0, stream>>>(QKV, Ob);
    // H+W axes: one N=1536 GEMM (weight rows adjacent), one fused attention
    gemm_bt<0, 256, 8><<<dim3(320, 6), 256, 0, stream>>>(
        xb, wqp + (size_t)(l * 3 + 1) * 196608, QKV, nullptr, nullptr, nullptr, QLD);
    attn_hw<<<2560, 256, 0, stream>>>(QKV, Ob);
    // merged out-projection (K=768)
    if (l == 0)
      gemm_bt<3, 128, 24><<<dim3(320, 2), 256, 0, stream>>>(
          Ob, wop, xb, bsum, nullptr, nullptr, 256);
    else
      gemm_bt<4, 128, 24><<<dim3(320, 2), 256, 0, stream>>>(
          Ob, wop + 196608, nullptr, bsum + 256, dec_w, logit, 0);
  }

  sigmoid_kernel<<<NPOS / 256, 256, 0, stream>>>(logit, dec_b, out);
}

// Round 7
// 344.286 us; speedup vs baseline: 1.8724x; 1.8724x over previous
//
#include <hip/hip_runtime.h>
#include <stdint.h>

typedef unsigned short u16;
typedef u16 u16x8 __attribute__((ext_vector_type(8)));
typedef __bf16 bf16x8 __attribute__((ext_vector_type(8)));
typedef float f32x4 __attribute__((ext_vector_type(4)));
typedef float f32x16 __attribute__((ext_vector_type(16)));

#define NE   256
#define NPOS 40960     // 32*64*4*5
#define QLD  1536      // QKV row stride

__device__ __forceinline__ float bf2f(u16 h) {
  union { unsigned u; float f; } c; c.u = ((unsigned)h) << 16; return c.f;
}
__device__ __forceinline__ u16 f2bf(float f) {
  union { float f; unsigned u; } c; c.f = f;
  unsigned u = c.u;
  return (u16)((u + 0x7FFFu + ((u >> 16) & 1u)) >> 16);
}
__device__ __forceinline__ unsigned pkbf(float a, float b) {
  unsigned r;
  asm("v_cvt_pk_bf16_f32 %0, %1, %2" : "=v"(r) : "v"(a), "v"(b));
  return r;
}
__device__ __forceinline__ void gll16(const void* g, void* l) {
  __builtin_amdgcn_global_load_lds(
      (const __attribute__((address_space(1))) void*)g,
      (__attribute__((address_space(3))) void*)l, 16, 0, 0);
}
template<int N> __device__ __forceinline__ void waitvm() {
  if constexpr (N == 0)       asm volatile("s_waitcnt vmcnt(0)"  ::: "memory");
  else if constexpr (N == 4)  asm volatile("s_waitcnt vmcnt(4)"  ::: "memory");
  else if constexpr (N == 6)  asm volatile("s_waitcnt vmcnt(6)"  ::: "memory");
  else if constexpr (N == 8)  asm volatile("s_waitcnt vmcnt(8)"  ::: "memory");
  else if constexpr (N == 12) asm volatile("s_waitcnt vmcnt(12)" ::: "memory");
}

// ---------------------------------------------------------------------------
// prep: xb[n][e] = bf16(x[b,s,e,h,w] + pos), n = ((b*64+s)*4+h)*5+w
// ---------------------------------------------------------------------------
__global__ __launch_bounds__(256) void prep_kernel(
    const float* __restrict__ x, const float* __restrict__ pos_s,
    const float* __restrict__ pos_h, const float* __restrict__ pos_w,
    u16* __restrict__ xb)
{
  __shared__ float Ls[256 * 21];
  const int bs = blockIdx.x;           // b*64+s
  const int s  = bs & 63;
  const int tid = threadIdx.x;
  const float* xp = x + (size_t)bs * 5120;
  for (int i = tid; i < 5120; i += 256) {
    int e = i / 20, hw = i % 20;
    int h = hw / 5, w = hw % 5;
    float v = xp[i] + pos_s[s * 256 + e] + pos_h[e * 4 + h] + pos_w[e * 5 + w];
    Ls[e * 21 + hw] = v;
  }
  __syncthreads();
  u16* op = xb + (size_t)bs * 20 * 256;
  for (int i = tid; i < 5120; i += 256) {
    int nl = i >> 8, e = i & 255;
    op[nl * 256 + e] = f2bf(Ls[e * 21 + nl]);
  }
}

// ---------------------------------------------------------------------------
// weight packing; wq rows scaled by 0.25 (attention SCALE folded in)
// ---------------------------------------------------------------------------
__global__ __launch_bounds__(256) void pack_qkv(
    const float* __restrict__ wq, const float* __restrict__ wkv, u16* __restrict__ dst)
{
  int i = blockIdx.x * 256 + threadIdx.x;      // 6*768*256
  int la = i / (768 * 256);
  int rem = i - la * (768 * 256);
  int r = rem >> 8, c = rem & 255;
  float v = (r < 256) ? wq[(size_t)la * 65536 + r * 256 + c] * 0.25f
                      : wkv[(size_t)la * 131072 + (r - 256) * 256 + c];
  dst[i] = f2bf(v);
}

// merged out-proj weights: dst[l][out][a*256+in] = wo_w[l][a][out][in]
__global__ __launch_bounds__(256) void pack_wo(
    const float* __restrict__ wo, u16* __restrict__ dst)
{
  int i = blockIdx.x * 256 + threadIdx.x;      // 2*256*768
  int l = i / 196608;
  int rem = i - l * 196608;
  int out = rem / 768, k = rem % 768;
  int a = k >> 8, in = k & 255;
  dst[i] = f2bf(wo[(size_t)(((l * 3 + a) * 256) + out) * 256 + in]);
}

__global__ __launch_bounds__(256) void pack_bias(
    const float* __restrict__ wo_b, float* __restrict__ bsum)
{
  int i = blockIdx.x * 256 + threadIdx.x;      // 512
  if (i < 512) {
    int l = i >> 8, c = i & 255;
    bsum[i] = wo_b[(l * 3 + 0) * 256 + c] + wo_b[(l * 3 + 1) * 256 + c]
            + wo_b[(l * 3 + 2) * 256 + c];
  }
}

// ---------------------------------------------------------------------------
// GEMM: C[M][N] = A[M][K] * B[N][K]^T   (A,B bf16; acc f32)
// 128 x BN tile, K = NKT*32, TRIPLE-buffered LDS, 2-deep counted-vmcnt
// prefetch (tile k's loads get ~2 compute phases to land).
// MODE 0: store bf16 at ldc; 3: Cb = bf16(acc+bias); 4: fused decode partial
// ---------------------------------------------------------------------------
template<int MODE, int BN, int NKT>
__global__ __launch_bounds__(256, 2) void gemm_bt(
    const u16* __restrict__ A, const u16* __restrict__ B,
    u16* __restrict__ Cb, const float* __restrict__ bias,
    const float* __restrict__ dw, float* __restrict__ logit,
    int ldc)
{
  constexpr int K   = NKT * 32;
  constexpr int NF  = BN / 32;          // n-frags per wave (wave covers BN/2)
  constexpr int LPT = 2 + BN / 64;      // gll16 per thread per k-tile
  constexpr int ASZ = 128 * 32;         // u16 per A slice
  constexpr int TSZ = (128 + BN) * 32;  // u16 per buffer (A then B)
  static_assert(MODE != 4 || BN == 128, "");
  static_assert(NKT >= 2, "");

  __shared__ alignas(16) u16 smem[3 * TSZ];

  const int tid  = threadIdx.x;
  const int bm   = blockIdx.x, bn = blockIdx.y;
  const int lane = tid & 63, w = tid >> 6;
  const int wr   = (w >> 1) * 64, wc = (w & 1) * (BN / 2);
  const int r16  = lane & 15, khi = lane >> 4;

  f32x4 acc[4][NF] = {};

  const u16* gA = A + (size_t)bm * 128 * K;
  const u16* gB = B + (size_t)bn * BN * K;

  auto STAGE = [&](int kt, int which) {
    u16* As = smem + which * TSZ;
    u16* Bs = As + ASZ;
    const u16* tA = gA + kt * 32;
    const u16* tB = gB + kt * 32;
    #pragma unroll
    for (int r = 0; r < 2; ++r) {
      int i = tid + r * 256;             // 0..511
      int row = i >> 2, seg = (i & 3) << 3;
      gll16(tA + (size_t)row * K + seg, (char*)As + i * 16);
    }
    #pragma unroll
    for (int r = 0; r < BN / 64; ++r) {
      int i = tid + r * 256;             // 0..BN*4-1
      int row = i >> 2, seg = (i & 3) << 3;
      gll16(tB + (size_t)row * K + seg, (char*)Bs + i * 16);
    }
  };

  STAGE(0, 0);
  STAGE(1, 1);
  #pragma unroll
  for (int kt = 0; kt < NKT; ++kt) {
    const int cur = kt % 3;
    if (kt + 2 < NKT)      { STAGE(kt + 2, (kt + 2) % 3); waitvm<2 * LPT>(); }
    else if (kt + 1 < NKT) { waitvm<LPT>(); }
    else                   { waitvm<0>(); }
    __builtin_amdgcn_s_barrier();
    asm volatile("" ::: "memory");

    const u16* As = smem + cur * TSZ;
    const u16* Bs = As + ASZ;
    bf16x8 af[4], bfr[NF];
    #pragma unroll
    for (int m = 0; m < 4; ++m)
      af[m] = *(const bf16x8*)(As + (wr + m * 16 + r16) * 32 + khi * 8);
    #pragma unroll
    for (int n = 0; n < NF; ++n)
      bfr[n] = *(const bf16x8*)(Bs + (wc + n * 16 + r16) * 32 + khi * 8);
    #pragma unroll
    for (int m = 0; m < 4; ++m)
      #pragma unroll
      for (int n = 0; n < NF; ++n)
        acc[m][n] = __builtin_amdgcn_mfma_f32_16x16x32_bf16(af[m], bfr[n], acc[m][n], 0, 0, 0);

    asm volatile("" ::: "memory");
    __builtin_amdgcn_s_barrier();
  }

  const int row0 = bm * 128 + wr + khi * 4;
  const int col0 = bn * BN + wc + r16;

  if constexpr (MODE == 4) {
    // fused decode: logit[r] += sum_c (acc + bias[c]) * dec_w[c]
    float dwv[NF], bvv[NF];
    #pragma unroll
    for (int n = 0; n < NF; ++n) {
      int c = col0 + n * 16;
      dwv[n] = dw[c];
      bvv[n] = bias[c];
    }
    #pragma unroll
    for (int m = 0; m < 4; ++m) {
      #pragma unroll
      for (int j = 0; j < 4; ++j) {
        float p = 0.f;
        #pragma unroll
        for (int n = 0; n < NF; ++n) p += (acc[m][n][j] + bvv[n]) * dwv[n];
        p += __shfl_xor(p, 1);
        p += __shfl_xor(p, 2);
        p += __shfl_xor(p, 4);
        p += __shfl_xor(p, 8);
        if (r16 == 0) atomicAdd(&logit[row0 + m * 16 + j], p);
      }
    }
  } else {
    #pragma unroll
    for (int m = 0; m < 4; ++m) {
      #pragma unroll
      for (int n = 0; n < NF; ++n) {
        int c = col0 + n * 16;
        float bv = (MODE == 3) ? bias[c] : 0.f;
        #pragma unroll
        for (int j = 0; j < 4; ++j) {
          int r = row0 + m * 16 + j;
          Cb[(size_t)r * ldc + c] = f2bf(acc[m][n][j] + bv);
        }
      }
    }
  }
}

// ---------------------------------------------------------------------------
// seq-axis attention via MFMA. One wave = one (group g, head hd).
// QKV [NPOS][QLD] bf16 (q|k|v in cols 0..767). Writes Ob cols 0..255 (ld 768).
// ---------------------------------------------------------------------------
__global__ __launch_bounds__(256) void attn_seq_mfma(
    const u16* __restrict__ QKV, u16* __restrict__ Ob)
{
  const int w = threadIdx.x >> 6, lane = threadIdx.x & 63;
  const int wid = blockIdx.x * 4 + w;
  const int hd = wid & 15, g = wid >> 4;          // g in [0,640)
  const int gb = g / 20, gr = g % 20;
  const int nbase = gb * 1280 + gr;               // + pos*20
  const int lo = lane & 31, hi = lane >> 5;

  bf16x8 kf[2], qf[2];
  #pragma unroll
  for (int t = 0; t < 2; ++t) {
    size_t r = (size_t)(nbase + (lo + 32 * t) * 20) * QLD;
    kf[t] = *(const bf16x8*)(QKV + r + 256 + hd * 16 + hi * 8);
    qf[t] = *(const bf16x8*)(QKV + r +       hd * 16 + hi * 8);
  }
  union { u16 a[8]; bf16x8 v; } vt[4];
  #pragma unroll
  for (int c = 0; c < 4; ++c)
    #pragma unroll
    for (int j = 0; j < 8; ++j)
      vt[c].a[j] = QKV[(size_t)(nbase + (c * 16 + hi * 8 + j) * 20) * QLD
                       + 512 + hd * 16 + lo];

  f32x16 s00 = {}, s10 = {}, s01 = {}, s11 = {};   // s[kt][qt]
  s00 = __builtin_amdgcn_mfma_f32_32x32x16_bf16(kf[0], qf[0], s00, 0, 0, 0);
  s10 = __builtin_amdgcn_mfma_f32_32x32x16_bf16(kf[1], qf[0], s10, 0, 0, 0);
  s01 = __builtin_amdgcn_mfma_f32_32x32x16_bf16(kf[0], qf[1], s01, 0, 0, 0);
  s11 = __builtin_amdgcn_mfma_f32_32x32x16_bf16(kf[1], qf[1], s11, 0, 0, 0);

  auto run_qt = [&](f32x16 t0, f32x16 t1, int qt) {
    float m = -1e30f;
    #pragma unroll
    for (int r = 0; r < 16; ++r) { m = fmaxf(m, t0[r]); m = fmaxf(m, t1[r]); }
    m = fmaxf(m, __shfl_xor(m, 32));
    const float C = 1.4426950408889634f;           // log2(e); 0.25 folded in wq
    float mc = m * C;
    float sum = 0.f;
    #pragma unroll
    for (int r = 0; r < 16; ++r) {
      float p0 = __builtin_amdgcn_exp2f(t0[r] * C - mc);
      float p1 = __builtin_amdgcn_exp2f(t1[r] * C - mc);
      t0[r] = p0; t1[r] = p1; sum += p0; sum += p1;
    }
    sum += __shfl_xor(sum, 32);
    float inv = __builtin_amdgcn_rcpf(sum);
    #pragma unroll
    for (int r = 0; r < 16; ++r) { t0[r] *= inv; t1[r] *= inv; }

    f32x16 oa = {};
    #pragma unroll
    for (int c = 0; c < 4; ++c) {
      const int rb = 8 * (c & 1);
      const f32x16& tt = (c < 2) ? t0 : t1;
      unsigned X0 = pkbf(tt[rb + 0], tt[rb + 1]);
      unsigned X1 = pkbf(tt[rb + 2], tt[rb + 3]);
      unsigned Y0 = pkbf(tt[rb + 4], tt[rb + 5]);
      unsigned Y1 = pkbf(tt[rb + 6], tt[rb + 7]);
      unsigned X0p = __shfl_xor((int)X0, 32), X1p = __shfl_xor((int)X1, 32);
      unsigned Y0p = __shfl_xor((int)Y0, 32), Y1p = __shfl_xor((int)Y1, 32);
      union { unsigned u[4]; bf16x8 v; } pf;
      pf.u[0] = hi ? Y0p : X0;
      pf.u[1] = hi ? Y1p : X1;
      pf.u[2] = hi ? Y0  : X0p;
      pf.u[3] = hi ? Y1  : X1p;
      oa = __builtin_amdgcn_mfma_f32_32x32x16_bf16(vt[c].v, pf.v, oa, 0, 0, 0);
    }
    unsigned P0 = pkbf(oa[0], oa[1]);
    unsigned P1 = pkbf(oa[2], oa[3]);
    unsigned P2 = pkbf(oa[4], oa[5]);
    unsigned P3 = pkbf(oa[6], oa[7]);
    unsigned sP0 = __shfl_xor((int)P0, 32), sP1 = __shfl_xor((int)P1, 32);
    unsigned sP2 = __shfl_xor((int)P2, 32), sP3 = __shfl_xor((int)P3, 32);
    union { unsigned u[4]; u16x8 v; } ov;
    ov.u[0] = hi ? sP2 : P0;
    ov.u[1] = hi ? sP3 : P1;
    ov.u[2] = hi ? P2  : sP0;
    ov.u[3] = hi ? P3  : sP1;
    u16* po = Ob + (size_t)(nbase + (qt * 32 + lo) * 20) * 768 + hd * 16 + hi * 8;
    *(u16x8*)po = ov.v;
  };
  run_qt(s00, s10, 0);
  run_qt(s01, s11, 1);
}

// ---------------------------------------------------------------------------
// H (T=4, stride 5) and W (T=5, stride 1) attention, one thread per (n, head)
// ---------------------------------------------------------------------------
template<int T>
__device__ __forceinline__ void attn1(
    const u16* __restrict__ QKV, int n, int base, int stp, int hd,
    u16* __restrict__ po)
{
  const u16* qp = QKV + (size_t)n * QLD + hd * 16;
  u16x8 q0 = *(const u16x8*)(qp), q1 = *(const u16x8*)(qp + 8);
  float q[16];
  #pragma unroll
  for (int d = 0; d < 8; ++d) { q[d] = bf2f(q0[d]); q[d + 8] = bf2f(q1[d]); }

  float s[T];
  float m = -1e30f;
  #pragma unroll
  for (int j = 0; j < T; ++j) {
    const u16* kp = QKV + (size_t)(base + j * stp) * QLD + 256 + hd * 16;
    u16x8 k0 = *(const u16x8*)(kp), k1 = *(const u16x8*)(kp + 8);
    float a = 0.f;
    #pragma unroll
    for (int d = 0; d < 8; ++d) a += q[d] * bf2f(k0[d]) + q[d + 8] * bf2f(k1[d]);
    s[j] = a;
    m = fmaxf(m, a);
  }
  float sum = 0.f;
  float o[16];
  #pragma unroll
  for (int d = 0; d < 16; ++d) o[d] = 0.f;
  #pragma unroll
  for (int j = 0; j < T; ++j) {
    float pj = __expf(s[j] - m);
    sum += pj;
    const u16* vp = QKV + (size_t)(base + j * stp) * QLD + 512 + hd * 16;
    u16x8 w0 = *(const u16x8*)(vp), w1 = *(const u16x8*)(vp + 8);
    #pragma unroll
    for (int d = 0; d < 8; ++d) { o[d] += pj * bf2f(w0[d]); o[d + 8] += pj * bf2f(w1[d]); }
  }
  float inv = 1.0f / sum;
  u16x8 r0, r1;
  #pragma unroll
  for (int d = 0; d < 8; ++d) { r0[d] = f2bf(o[d] * inv); r1[d] = f2bf(o[d + 8] * inv); }
  *(u16x8*)(po)     = r0;
  *(u16x8*)(po + 8) = r1;
}

__global__ __launch_bounds__(256) void attn_hw(
    const u16* __restrict__ QKV, u16* __restrict__ Ob)
{
  const int tg = blockIdx.x * 256 + threadIdx.x;   // n*16 + hd
  const int hd = tg & 15, n = tg >> 4;
  int h  = (n % 20) / 5;
  int w5 = n % 5;
  attn1<4>(QKV,       n, n - h * 5, 5, hd, Ob + (size_t)n * 768 + 256 + hd * 16);
  attn1<5>(QKV + 768, n, n - w5,    1, hd, Ob + (size_t)n * 768 + 512 + hd * 16);
}

// ---------------------------------------------------------------------------
// final sigmoid over accumulated logits
// ---------------------------------------------------------------------------
__global__ __launch_bounds__(256) void sigmoid_kernel(
    const float* __restrict__ logit, const float* __restrict__ dec_b,
    float* __restrict__ out)
{
  int i = blockIdx.x * 256 + threadIdx.x;
  out[i] = 1.0f / (1.0f + __expf(-(logit[i] + dec_b[0])));
}

// ---------------------------------------------------------------------------
extern "C" void kernel_launch(void* const* d_in, const int* in_sizes, int n_in,
                              void* d_out, int out_size, void* d_ws, size_t ws_size,
                              hipStream_t stream) {
  const float* x     = (const float*)d_in[0];
  const float* pos_s = (const float*)d_in[1];
  const float* pos_h = (const float*)d_in[2];
  const float* pos_w = (const float*)d_in[3];
  const float* wq    = (const float*)d_in[4];   // (2,3,256,256)
  const float* wkv   = (const float*)d_in[5];   // (2,3,512,256)
  const float* wo_w  = (const float*)d_in[6];   // (2,3,256,256)
  const float* wo_b  = (const float*)d_in[7];   // (2,3,256)
  const float* dec_w = (const float*)d_in[8];   // (1,256)
  const float* dec_b = (const float*)d_in[9];   // (1,)
  float* out = (float*)d_out;

  char* ws = (char*)d_ws;
  u16*   xb    = (u16*)ws;                       // 20,971,520
  u16*   Ob    = (u16*)(ws + 20971520);          // 62,914,560
  u16*   QKV   = (u16*)(ws + 83886080);          // 40960*1536*2 = 125,829,120
  u16*   wqp   = (u16*)(ws + 209715200);         // 2,359,296
  u16*   wop   = (u16*)(ws + 212074496);         // 786,432
  float* bsum  = (float*)(ws + 212860928);       // 2,048
  float* logit = (float*)(ws + 212862976);       // 163,840  (end ~213 MB)

  prep_kernel<<<2048, 256, 0, stream>>>(x, pos_s, pos_h, pos_w, xb);
  pack_qkv<<<4608, 256, 0, stream>>>(wq, wkv, wqp);
  pack_wo<<<1536, 256, 0, stream>>>(wo_w, wop);
  pack_bias<<<2, 256, 0, stream>>>(wo_b, bsum);
  hipMemsetAsync(logit, 0, NPOS * sizeof(float), stream);

  for (int l = 0; l < 2; ++l) {
    // seq axis: QKV cols 0..767 (ldc 1536), then MFMA attention
    gemm_bt<0, 256, 8><<<dim3(320, 3), 256, 0, stream>>>(
        xb, wqp + (size_t)(l * 3) * 196608, QKV, nullptr, nullptr, nullptr, QLD);
    attn_seq_mfma<<<2560, 256, 0, stream>>>(QKV, Ob);
    // H+W axes: one N=1536 GEMM (weight rows adjacent), one fused attention
    gemm_bt<0, 256, 8><<<dim3(320, 6), 256, 0, stream>>>(
        xb, wqp + (size_t)(l * 3 + 1) * 196608, QKV, nullptr, nullptr, nullptr, QLD);
    attn_hw<<<2560, 256, 0, stream>>>(QKV, Ob);
    // merged out-projection (K=768)
    if (l == 0)
      gemm_bt<3, 128, 24><<<dim3(320, 2), 256, 0, stream>>>(
          Ob, wop, xb, bsum, nullptr, nullptr, 256);
    else
      gemm_bt<4, 128, 24><<<dim3(320, 2), 256, 0, stream>>>(
          Ob, wop + 196608, nullptr, bsum + 256, dec_w, logit, 0);
  }

  sigmoid_kernel<<<NPOS / 256, 256, 0, stream>>>(logit, dec_b, out);
}